// Round 1
// baseline (510.403 us; speedup 1.0000x reference)
//
#include <hip/hip_runtime.h>
#include <hip/hip_bf16.h>
#include <cstdint>
#include <cstddef>

#define DIMM 2048
#define NHEADS 32
#define HDIM 64
#define SEQ 2048
#define NBATCH 2
#define ROWS 4096
#define NFREQ 16

typedef __bf16 bfv8 __attribute__((ext_vector_type(8)));
typedef float f32x4v __attribute__((ext_vector_type(4)));

__device__ __forceinline__ void gload16(const void* g, void* l) {
  __builtin_amdgcn_global_load_lds((const __attribute__((address_space(1))) void*)g,
                                   (__attribute__((address_space(3))) void*)l, 16, 0, 0);
}

__device__ __forceinline__ f32x4v mfma16(bfv8 a, bfv8 b, f32x4v c) {
  return __builtin_amdgcn_mfma_f32_16x16x32_bf16(a, b, c, 0, 0, 0);
}

__device__ __forceinline__ unsigned short f2bfu(float f) {
  __hip_bfloat16 h = __float2bfloat16(f);
  return __builtin_bit_cast(unsigned short, h);
}

// ---------------- RoPE cos/sin table: [SEQ][16] f32 each ----------------
__global__ __launch_bounds__(256) void rope_tab_kernel(float* __restrict__ ct,
                                                       float* __restrict__ st) {
  const int i = blockIdx.x * 256 + threadIdx.x;
  if (i >= SEQ * NFREQ) return;
  const int pos = i >> 4, f = i & 15;
  const float freq = powf(10000.0f, -(float)f / 16.0f);
  const float ang = (float)pos * freq;
  ct[i] = cosf(ang);
  st[i] = sinf(ang);
}

// ---------------- transpose + cast f32[K][N] -> bf16[N][K] ----------------
__global__ __launch_bounds__(256) void transpose_cast_kernel(const float* __restrict__ W,
                                                             __hip_bfloat16* __restrict__ WT,
                                                             int K, int N) {
  __shared__ float tile[32][33];
  const int n0 = blockIdx.x * 32, k0 = blockIdx.y * 32;
  const int tx = threadIdx.x, ty = threadIdx.y;
#pragma unroll
  for (int j = 0; j < 4; ++j)
    tile[ty + j * 8][tx] = W[(size_t)(k0 + ty + j * 8) * N + n0 + tx];
  __syncthreads();
#pragma unroll
  for (int j = 0; j < 4; ++j)
    WT[(size_t)(n0 + ty + j * 8) * K + k0 + tx] = __float2bfloat16(tile[tx][ty + j * 8]);
}

// ---------------- LayerNorm f32 -> bf16, one row per block ----------------
__global__ __launch_bounds__(256) void ln_kernel(const float* __restrict__ x,
                                                 const float* __restrict__ lw,
                                                 const float* __restrict__ lb,
                                                 __hip_bfloat16* __restrict__ h) {
  const int row = blockIdx.x;
  const int t = threadIdx.x;
  const float4* xr = (const float4*)(x + (size_t)row * DIMM);
  float4 a = xr[t * 2], b = xr[t * 2 + 1];
  float e[8];
  *(float4*)e = a; *(float4*)(e + 4) = b;
  float s = 0.f, ss = 0.f;
#pragma unroll
  for (int j = 0; j < 8; ++j) { s += e[j]; ss += e[j] * e[j]; }
#pragma unroll
  for (int o = 1; o < 64; o <<= 1) { s += __shfl_xor(s, o); ss += __shfl_xor(ss, o); }
  __shared__ float red[8];
  const int wid = t >> 6;
  if ((t & 63) == 0) { red[wid * 2] = s; red[wid * 2 + 1] = ss; }
  __syncthreads();
  s = red[0] + red[2] + red[4] + red[6];
  ss = red[1] + red[3] + red[5] + red[7];
  const float mu = s * (1.f / DIMM);
  const float var = ss * (1.f / DIMM) - mu * mu;
  const float rs = rsqrtf(var + 1e-5f);
  const float4* w4 = (const float4*)lw;
  const float4* b4 = (const float4*)lb;
  float4 wa = w4[t * 2], wb = w4[t * 2 + 1], ba = b4[t * 2], bb = b4[t * 2 + 1];
  float wv[8], bv[8];
  *(float4*)wv = wa; *(float4*)(wv + 4) = wb;
  *(float4*)bv = ba; *(float4*)(bv + 4) = bb;
  unsigned short hv[8];
#pragma unroll
  for (int j = 0; j < 8; ++j)
    hv[j] = f2bfu((e[j] - mu) * rs * wv[j] + bv[j]);
  *(uint4*)((char*)h + (size_t)row * (DIMM * 2) + t * 16) = *(uint4*)hv;
}

// ---------------- shared 128x128xK GEMM main loop (A row-major MxK, BT row-major NxK) ----
// LDS tiles are [128 rows][128 bytes] with XOR swizzle: phys = L ^ ((row&7)<<4).
// Staged via global_load_lds (linear dest) with inverse-swizzled global source.
__device__ __forceinline__ void gemm_tile(const __hip_bfloat16* __restrict__ A,
                                          const __hip_bfloat16* __restrict__ BT,
                                          const int K, const int brow, const int bcol,
                                          char* ldsA, char* ldsB, f32x4v acc[4][4]) {
  const int tid = threadIdx.x;
  const int lane = tid & 63, wid = tid >> 6;
  const int g = lane >> 4, ln15 = lane & 15;
  const int wr = wid >> 1, wc = wid & 1;
  for (int k0 = 0; k0 < K; k0 += 64) {
    __syncthreads();
#pragma unroll
    for (int i = 0; i < 4; ++i) {
      const int f = wid * 4096 + i * 1024 + lane * 16;
      const int row = f >> 7;
      const int kb = (f & 127) ^ ((row & 7) << 4);
      gload16((const char*)A + ((size_t)(brow + row) * K + k0) * 2 + kb,
              ldsA + wid * 4096 + i * 1024);
      gload16((const char*)BT + ((size_t)(bcol + row) * K + k0) * 2 + kb,
              ldsB + wid * 4096 + i * 1024);
    }
    asm volatile("s_waitcnt vmcnt(0)" ::: "memory");
    __syncthreads();
    bfv8 av[2][4], bv[2][4];
#pragma unroll
    for (int ks = 0; ks < 2; ++ks) {
#pragma unroll
      for (int q = 0; q < 4; ++q) {
        const int ra = wr * 64 + q * 16 + ln15;
        av[ks][q] = *(const bfv8*)(ldsA + ((size_t)ra << 7) + ((ks * 64 + g * 16) ^ ((ra & 7) << 4)));
        const int rb = wc * 64 + q * 16 + ln15;
        bv[ks][q] = *(const bfv8*)(ldsB + ((size_t)rb << 7) + ((ks * 64 + g * 16) ^ ((rb & 7) << 4)));
      }
    }
#pragma unroll
    for (int mf = 0; mf < 4; ++mf)
#pragma unroll
      for (int nf = 0; nf < 4; ++nf) {
        acc[mf][nf] = mfma16(av[0][mf], bv[0][nf], acc[mf][nf]);
        acc[mf][nf] = mfma16(av[1][mf], bv[1][nf], acc[mf][nf]);
      }
  }
}

// ---------------- QKV GEMM + bias + RoPE + scatter to q/k/v [n*h][s][64] bf16 --------
__global__ __launch_bounds__(256) void gemm_qkv_kernel(
    const __hip_bfloat16* __restrict__ A, const __hip_bfloat16* __restrict__ BT,
    const float* __restrict__ bqkv, const float* __restrict__ ct, const float* __restrict__ st,
    __hip_bfloat16* __restrict__ qb, __hip_bfloat16* __restrict__ kb,
    __hip_bfloat16* __restrict__ vb) {
  __shared__ char lds[32768];
  const f32x4v fz = {0.f, 0.f, 0.f, 0.f};
  f32x4v acc[4][4];
#pragma unroll
  for (int mf = 0; mf < 4; ++mf)
#pragma unroll
    for (int nf = 0; nf < 4; ++nf) acc[mf][nf] = fz;
  const int brow = blockIdx.y * 128, bcol = blockIdx.x * 128;
  gemm_tile(A, BT, DIMM, brow, bcol, lds, lds + 16384, acc);

  const int tid = threadIdx.x, lane = tid & 63, wid = tid >> 6;
  const int g = lane >> 4, ln15 = lane & 15;
  const int wr = wid >> 1, wc = wid & 1;
  const int cb = bcol + wc * 64;              // 64-aligned global col base
  const int which = cb >> 11;                 // 0=q 1=k 2=v
  const int head = (cb & 2047) >> 6;
  __hip_bfloat16* dst = (which == 0) ? qb : (which == 1) ? kb : vb;
  float bias[4];
#pragma unroll
  for (int nf = 0; nf < 4; ++nf) bias[nf] = bqkv[cb + nf * 16 + ln15];
#pragma unroll
  for (int mf = 0; mf < 4; ++mf)
#pragma unroll
    for (int r = 0; r < 4; ++r) {
      const int row = brow + wr * 64 + mf * 16 + g * 4 + r;
      const int nidx = row >> 11, pos = row & 2047;
      float v0 = acc[mf][0][r] + bias[0];
      float v1 = acc[mf][1][r] + bias[1];
      float v2 = acc[mf][2][r] + bias[2];
      float v3 = acc[mf][3][r] + bias[3];
      if (which < 2) {  // RoPE on q,k: d=ln15 pairs with d+16
        const float c0 = ct[pos * 16 + ln15], s0 = st[pos * 16 + ln15];
        const float x1 = v0, x2 = v1;
        v0 = x1 * c0 - x2 * s0;
        v1 = x2 * c0 + x1 * s0;
      }
      __hip_bfloat16* p = dst + (((size_t)(nidx * NHEADS + head)) * SEQ + pos) * HDIM;
      p[ln15] = __float2bfloat16(v0);
      p[16 + ln15] = __float2bfloat16(v1);
      p[32 + ln15] = __float2bfloat16(v2);
      p[48 + ln15] = __float2bfloat16(v3);
    }
}

// ---------------- out-proj GEMM + bias + residual -> f32 out ----------------
__global__ __launch_bounds__(256) void gemm_out_kernel(
    const __hip_bfloat16* __restrict__ A, const __hip_bfloat16* __restrict__ BT,
    const float* __restrict__ bout, const float* __restrict__ skip,
    float* __restrict__ out) {
  __shared__ char lds[32768];
  const f32x4v fz = {0.f, 0.f, 0.f, 0.f};
  f32x4v acc[4][4];
#pragma unroll
  for (int mf = 0; mf < 4; ++mf)
#pragma unroll
    for (int nf = 0; nf < 4; ++nf) acc[mf][nf] = fz;
  const int brow = blockIdx.y * 128, bcol = blockIdx.x * 128;
  gemm_tile(A, BT, DIMM, brow, bcol, lds, lds + 16384, acc);

  const int tid = threadIdx.x, lane = tid & 63, wid = tid >> 6;
  const int g = lane >> 4, ln15 = lane & 15;
  const int wr = wid >> 1, wc = wid & 1;
#pragma unroll
  for (int mf = 0; mf < 4; ++mf)
#pragma unroll
    for (int r = 0; r < 4; ++r) {
      const int row = brow + wr * 64 + mf * 16 + g * 4 + r;
      const float* xr = skip + (size_t)row * DIMM;
      float* orow = out + (size_t)row * DIMM;
#pragma unroll
      for (int nf = 0; nf < 4; ++nf) {
        const int c = bcol + wc * 64 + nf * 16 + ln15;
        orow[c] = acc[mf][nf][r] + bout[c] + xr[c];
      }
    }
}

// ---------------- causal flash attention: one 64-q-row tile per block ----------------
__global__ __launch_bounds__(256) void attn_kernel(
    const __hip_bfloat16* __restrict__ qb, const __hip_bfloat16* __restrict__ kb,
    const __hip_bfloat16* __restrict__ vb, __hip_bfloat16* __restrict__ ob) {
  __shared__ char sm[32768];
  char* Qs = sm;            // 8KB [64][128B] swizzled
  char* Ks = sm + 8192;     // 8KB
  char* VT = sm + 16384;    // 8KB transposed V [d=64][128B] swizzled
  char* Ps = sm + 24576;    // 4 waves x 2KB  P[16][128B] swizzled
  const int tid = threadIdx.x, lane = tid & 63, wid = tid >> 6;
  const int g = lane >> 4, ln15 = lane & 15;
  const int bid = blockIdx.x;
  const int qt = bid & 31, nh = bid >> 5;
  const size_t hb = (size_t)nh * SEQ * HDIM;
  const char* Qg = (const char*)(qb + hb + (size_t)qt * 64 * HDIM);
#pragma unroll
  for (int i = 0; i < 2; ++i) {
    const int fo = wid * 2048 + i * 1024 + lane * 16;
    const int row = fo >> 7;
    const int kbyt = (fo & 127) ^ ((row & 7) << 4);
    gload16(Qg + row * 128 + kbyt, Qs + wid * 2048 + i * 1024);
  }
  asm volatile("s_waitcnt vmcnt(0)" ::: "memory");
  __syncthreads();
  bfv8 aq[2];
  {
    const int row = wid * 16 + ln15;
    aq[0] = *(const bfv8*)(Qs + (row << 7) + ((g * 16) ^ ((row & 7) << 4)));
    aq[1] = *(const bfv8*)(Qs + (row << 7) + ((64 + g * 16) ^ ((row & 7) << 4)));
  }
  const f32x4v fz = {0.f, 0.f, 0.f, 0.f};
  f32x4v oa[4];
  float m[4], l[4];
#pragma unroll
  for (int r = 0; r < 4; ++r) { m[r] = -__builtin_inff(); l[r] = 0.f; }
#pragma unroll
  for (int nf = 0; nf < 4; ++nf) oa[nf] = fz;
  const float scale = 0.125f;
  const int qrow0 = qt * 64 + wid * 16 + g * 4;
  for (int kt = 0; kt <= qt; ++kt) {
    __syncthreads();
    const char* Kg = (const char*)(kb + hb + (size_t)kt * 64 * HDIM);
#pragma unroll
    for (int i = 0; i < 2; ++i) {
      const int fo = wid * 2048 + i * 1024 + lane * 16;
      const int row = fo >> 7;
      const int kbyt = (fo & 127) ^ ((row & 7) << 4);
      gload16(Kg + row * 128 + kbyt, Ks + wid * 2048 + i * 1024);
    }
    const char* Vg = (const char*)(vb + hb + (size_t)kt * 64 * HDIM);
#pragma unroll
    for (int i = 0; i < 2; ++i) {
      const int fo = (tid + i * 256) * 16;
      const int krow = fo >> 7;
      const int d0 = (fo & 127) >> 1;
      uint4 pix = *(const uint4*)(Vg + fo);
      const unsigned short* pv = (const unsigned short*)&pix;
#pragma unroll
      for (int j = 0; j < 8; ++j) {
        const int d = d0 + j;
        *(unsigned short*)(VT + (d << 7) + ((krow * 2) ^ ((d & 7) << 4))) = pv[j];
      }
    }
    asm volatile("s_waitcnt vmcnt(0)" ::: "memory");
    __syncthreads();
    f32x4v s[4];
#pragma unroll
    for (int nf = 0; nf < 4; ++nf) s[nf] = fz;
#pragma unroll
    for (int nf = 0; nf < 4; ++nf) {
      const int row = nf * 16 + ln15;
      const bfv8 bk0 = *(const bfv8*)(Ks + (row << 7) + ((g * 16) ^ ((row & 7) << 4)));
      const bfv8 bk1 = *(const bfv8*)(Ks + (row << 7) + ((64 + g * 16) ^ ((row & 7) << 4)));
      s[nf] = mfma16(aq[0], bk0, s[nf]);
      s[nf] = mfma16(aq[1], bk1, s[nf]);
    }
#pragma unroll
    for (int r = 0; r < 4; ++r) {
      float sv[4];
      float mx = -__builtin_inff();
#pragma unroll
      for (int nf = 0; nf < 4; ++nf) {
        const int kg = kt * 64 + nf * 16 + ln15;
        float v = s[nf][r] * scale;
        if (kg > qrow0 + r) v = -__builtin_inff();
        sv[nf] = v;
        mx = fmaxf(mx, v);
      }
#pragma unroll
      for (int o = 1; o < 16; o <<= 1) mx = fmaxf(mx, __shfl_xor(mx, o));
      const float mn = fmaxf(m[r], mx);
      const float al = __expf(m[r] - mn);
      float ps = 0.f;
#pragma unroll
      for (int nf = 0; nf < 4; ++nf) { sv[nf] = __expf(sv[nf] - mn); ps += sv[nf]; }
#pragma unroll
      for (int o = 1; o < 16; o <<= 1) ps += __shfl_xor(ps, o);
      l[r] = l[r] * al + ps;
      m[r] = mn;
#pragma unroll
      for (int nf = 0; nf < 4; ++nf) oa[nf][r] *= al;
      const int prow = g * 4 + r;
#pragma unroll
      for (int nf = 0; nf < 4; ++nf)
        *(unsigned short*)(Ps + wid * 2048 + (prow << 7) +
                           (((nf * 16 + ln15) * 2) ^ ((prow & 7) << 4))) = f2bfu(sv[nf]);
    }
    asm volatile("s_waitcnt lgkmcnt(0)" ::: "memory");
    const bfv8 ap0 = *(const bfv8*)(Ps + wid * 2048 + (ln15 << 7) + ((g * 16) ^ ((ln15 & 7) << 4)));
    const bfv8 ap1 = *(const bfv8*)(Ps + wid * 2048 + (ln15 << 7) + ((64 + g * 16) ^ ((ln15 & 7) << 4)));
#pragma unroll
    for (int nf = 0; nf < 4; ++nf) {
      const int d = nf * 16 + ln15;
      const bfv8 bv0 = *(const bfv8*)(VT + (d << 7) + ((g * 16) ^ ((d & 7) << 4)));
      const bfv8 bv1 = *(const bfv8*)(VT + (d << 7) + ((64 + g * 16) ^ ((d & 7) << 4)));
      oa[nf] = mfma16(ap0, bv0, oa[nf]);
      oa[nf] = mfma16(ap1, bv1, oa[nf]);
    }
  }
  const int nidx = nh >> 5, head = nh & 31;
#pragma unroll
  for (int r = 0; r < 4; ++r) {
    const int qg2 = qrow0 + r;
    const float inv = 1.f / l[r];
    __hip_bfloat16* prow_out = ob + ((size_t)nidx * SEQ + qg2) * DIMM + head * HDIM;
#pragma unroll
    for (int nf = 0; nf < 4; ++nf)
      prow_out[nf * 16 + ln15] = __float2bfloat16(oa[nf][r] * inv);
  }
}

extern "C" void kernel_launch(void* const* d_in, const int* in_sizes, int n_in,
                              void* d_out, int out_size, void* d_ws, size_t ws_size,
                              hipStream_t stream) {
  const float* x = (const float*)d_in[0];
  const float* ln_w = (const float*)d_in[1];
  const float* ln_b = (const float*)d_in[2];
  const float* w_qkv = (const float*)d_in[3];
  const float* b_qkv = (const float*)d_in[4];
  const float* w_out = (const float*)d_in[5];
  const float* b_out = (const float*)d_in[6];
  float* out = (float*)d_out;

  char* ws = (char*)d_ws;
  size_t off = 0;
  auto alloc = [&](size_t bytes) -> char* {
    char* p = ws + off;
    off += (bytes + 255) & ~(size_t)255;
    return p;
  };
  __hip_bfloat16* h = (__hip_bfloat16*)alloc((size_t)ROWS * DIMM * 2);
  __hip_bfloat16* wqkvT = (__hip_bfloat16*)alloc((size_t)3 * DIMM * DIMM * 2);
  __hip_bfloat16* woutT = (__hip_bfloat16*)alloc((size_t)DIMM * DIMM * 2);
  __hip_bfloat16* qbuf = (__hip_bfloat16*)alloc((size_t)ROWS * DIMM * 2);
  __hip_bfloat16* kbuf = (__hip_bfloat16*)alloc((size_t)ROWS * DIMM * 2);
  __hip_bfloat16* vbuf = (__hip_bfloat16*)alloc((size_t)ROWS * DIMM * 2);
  __hip_bfloat16* obuf = (__hip_bfloat16*)alloc((size_t)ROWS * DIMM * 2);
  float* ct = (float*)alloc((size_t)SEQ * NFREQ * 4);
  float* st = (float*)alloc((size_t)SEQ * NFREQ * 4);

  rope_tab_kernel<<<dim3((SEQ * NFREQ + 255) / 256), dim3(256), 0, stream>>>(ct, st);
  transpose_cast_kernel<<<dim3(3 * DIMM / 32, DIMM / 32), dim3(32, 8), 0, stream>>>(
      w_qkv, wqkvT, DIMM, 3 * DIMM);
  transpose_cast_kernel<<<dim3(DIMM / 32, DIMM / 32), dim3(32, 8), 0, stream>>>(
      w_out, woutT, DIMM, DIMM);
  ln_kernel<<<dim3(ROWS), dim3(256), 0, stream>>>(x, ln_w, ln_b, h);
  gemm_qkv_kernel<<<dim3(3 * DIMM / 128, ROWS / 128), dim3(256), 0, stream>>>(
      h, wqkvT, b_qkv, ct, st, qbuf, kbuf, vbuf);
  attn_kernel<<<dim3(NBATCH * NHEADS * (SEQ / 64)), dim3(256), 0, stream>>>(
      qbuf, kbuf, vbuf, obuf);
  gemm_out_kernel<<<dim3(DIMM / 128, ROWS / 128), dim3(256), 0, stream>>>(
      obuf, woutT, b_out, x, out);
}

// Round 3
// 293.210 us; speedup vs baseline: 1.7407x; 1.7407x over previous
//
#include <hip/hip_runtime.h>
#include <hip/hip_bf16.h>
#include <cstdint>
#include <cstddef>

#define DIMM 2048
#define NHEADS 32
#define HDIM 64
#define SEQ 2048
#define NBATCH 2
#define ROWS 4096
#define NFREQ 16

typedef __bf16 bfv8 __attribute__((ext_vector_type(8)));
typedef float f32x4v __attribute__((ext_vector_type(4)));
typedef float f32x16 __attribute__((ext_vector_type(16)));

__device__ __forceinline__ void gload16(const void* g, void* l) {
  __builtin_amdgcn_global_load_lds((const __attribute__((address_space(1))) void*)g,
                                   (__attribute__((address_space(3))) void*)l, 16, 0, 0);
}

__device__ __forceinline__ f32x4v mfma16(bfv8 a, bfv8 b, f32x4v c) {
  return __builtin_amdgcn_mfma_f32_16x16x32_bf16(a, b, c, 0, 0, 0);
}

__device__ __forceinline__ f32x16 mfma32(bfv8 a, bfv8 b, f32x16 c) {
  return __builtin_amdgcn_mfma_f32_32x32x16_bf16(a, b, c, 0, 0, 0);
}

__device__ __forceinline__ unsigned short f2bfu(float f) {
  __hip_bfloat16 h = __float2bfloat16(f);
  return __builtin_bit_cast(unsigned short, h);
}

__device__ __forceinline__ unsigned pack2bf(float a, float b) {
  return (unsigned)f2bfu(a) | ((unsigned)f2bfu(b) << 16);
}

// permlane32_swap semantics via shfl:
// new_a[l] = l<32 ? a[l] : b[l^32];  new_b[l] = l<32 ? a[l^32] : b[l]
__device__ __forceinline__ void swap32(unsigned& a, unsigned& b, const int hi) {
  const unsigned ta = (unsigned)__shfl_xor((int)a, 32);
  const unsigned tb = (unsigned)__shfl_xor((int)b, 32);
  const unsigned na = hi ? tb : a;
  const unsigned nb = hi ? b : ta;
  a = na;
  b = nb;
}

__device__ __forceinline__ void xcd_swizzle(int& bx, int& by) {
  const int gx = gridDim.x, nwg = gx * gridDim.y;
  const int orig = blockIdx.y * gx + blockIdx.x;
  const int q = nwg >> 3, r = nwg & 7;
  const int xcd = orig & 7, loc = orig >> 3;
  const int wg = (xcd < r ? xcd * (q + 1) : r * (q + 1) + (xcd - r) * q) + loc;
  bx = wg % gx;
  by = wg / gx;
}

// ---------------- RoPE cos/sin table: [SEQ][16] f32 each ----------------
__global__ __launch_bounds__(256) void rope_tab_kernel(float* __restrict__ ct,
                                                       float* __restrict__ st) {
  const int i = blockIdx.x * 256 + threadIdx.x;
  if (i >= SEQ * NFREQ) return;
  const int pos = i >> 4, f = i & 15;
  const float freq = powf(10000.0f, -(float)f / 16.0f);
  const float ang = (float)pos * freq;
  ct[i] = cosf(ang);
  st[i] = sinf(ang);
}

// ---------------- transpose + cast f32[K][N] -> bf16[N][K] ----------------
__global__ __launch_bounds__(256) void transpose_cast_kernel(const float* __restrict__ W,
                                                             __hip_bfloat16* __restrict__ WT,
                                                             int K, int N) {
  __shared__ float tile[32][33];
  const int n0 = blockIdx.x * 32, k0 = blockIdx.y * 32;
  const int tx = threadIdx.x, ty = threadIdx.y;
#pragma unroll
  for (int j = 0; j < 4; ++j)
    tile[ty + j * 8][tx] = W[(size_t)(k0 + ty + j * 8) * N + n0 + tx];
  __syncthreads();
#pragma unroll
  for (int j = 0; j < 4; ++j)
    WT[(size_t)(n0 + ty + j * 8) * K + k0 + tx] = __float2bfloat16(tile[tx][ty + j * 8]);
}

// ---------------- LayerNorm f32 -> bf16, one row per block ----------------
__global__ __launch_bounds__(256) void ln_kernel(const float* __restrict__ x,
                                                 const float* __restrict__ lw,
                                                 const float* __restrict__ lb,
                                                 __hip_bfloat16* __restrict__ h) {
  const int row = blockIdx.x;
  const int t = threadIdx.x;
  const float4* xr = (const float4*)(x + (size_t)row * DIMM);
  float4 a = xr[t * 2], b = xr[t * 2 + 1];
  float e[8];
  *(float4*)e = a; *(float4*)(e + 4) = b;
  float s = 0.f, ss = 0.f;
#pragma unroll
  for (int j = 0; j < 8; ++j) { s += e[j]; ss += e[j] * e[j]; }
#pragma unroll
  for (int o = 1; o < 64; o <<= 1) { s += __shfl_xor(s, o); ss += __shfl_xor(ss, o); }
  __shared__ float red[8];
  const int wid = t >> 6;
  if ((t & 63) == 0) { red[wid * 2] = s; red[wid * 2 + 1] = ss; }
  __syncthreads();
  s = red[0] + red[2] + red[4] + red[6];
  ss = red[1] + red[3] + red[5] + red[7];
  const float mu = s * (1.f / DIMM);
  const float var = ss * (1.f / DIMM) - mu * mu;
  const float rs = rsqrtf(var + 1e-5f);
  const float4* w4 = (const float4*)lw;
  const float4* b4 = (const float4*)lb;
  float4 wa = w4[t * 2], wb = w4[t * 2 + 1], ba = b4[t * 2], bb = b4[t * 2 + 1];
  float wv[8], bv[8];
  *(float4*)wv = wa; *(float4*)(wv + 4) = wb;
  *(float4*)bv = ba; *(float4*)(bv + 4) = bb;
  unsigned short hv[8];
#pragma unroll
  for (int j = 0; j < 8; ++j)
    hv[j] = f2bfu((e[j] - mu) * rs * wv[j] + bv[j]);
  *(uint4*)((char*)h + (size_t)row * (DIMM * 2) + t * 16) = *(uint4*)hv;
}

// ---------------- shared 128x128xK GEMM main loop ----------------
__device__ __forceinline__ void gemm_tile(const __hip_bfloat16* __restrict__ A,
                                          const __hip_bfloat16* __restrict__ BT,
                                          const int K, const int brow, const int bcol,
                                          char* ldsA, char* ldsB, f32x4v acc[4][4]) {
  const int tid = threadIdx.x;
  const int lane = tid & 63, wid = tid >> 6;
  const int g = lane >> 4, ln15 = lane & 15;
  const int wr = wid >> 1, wc = wid & 1;
  for (int k0 = 0; k0 < K; k0 += 64) {
    __syncthreads();
#pragma unroll
    for (int i = 0; i < 4; ++i) {
      const int f = wid * 4096 + i * 1024 + lane * 16;
      const int row = f >> 7;
      const int kb = (f & 127) ^ ((row & 7) << 4);
      gload16((const char*)A + ((size_t)(brow + row) * K + k0) * 2 + kb,
              ldsA + wid * 4096 + i * 1024);
      gload16((const char*)BT + ((size_t)(bcol + row) * K + k0) * 2 + kb,
              ldsB + wid * 4096 + i * 1024);
    }
    asm volatile("s_waitcnt vmcnt(0)" ::: "memory");
    __syncthreads();
    bfv8 av[2][4], bv[2][4];
#pragma unroll
    for (int ks = 0; ks < 2; ++ks) {
#pragma unroll
      for (int q = 0; q < 4; ++q) {
        const int ra = wr * 64 + q * 16 + ln15;
        av[ks][q] = *(const bfv8*)(ldsA + ((size_t)ra << 7) + ((ks * 64 + g * 16) ^ ((ra & 7) << 4)));
        const int rb = wc * 64 + q * 16 + ln15;
        bv[ks][q] = *(const bfv8*)(ldsB + ((size_t)rb << 7) + ((ks * 64 + g * 16) ^ ((rb & 7) << 4)));
      }
    }
#pragma unroll
    for (int mf = 0; mf < 4; ++mf)
#pragma unroll
      for (int nf = 0; nf < 4; ++nf) {
        acc[mf][nf] = mfma16(av[0][mf], bv[0][nf], acc[mf][nf]);
        acc[mf][nf] = mfma16(av[1][mf], bv[1][nf], acc[mf][nf]);
      }
  }
}

// ---------------- QKV GEMM + bias + RoPE; q,k -> [n*h][s][64]; v -> VT [n*h][64][s] ----
__global__ __launch_bounds__(256) void gemm_qkv_kernel(
    const __hip_bfloat16* __restrict__ A, const __hip_bfloat16* __restrict__ BT,
    const float* __restrict__ bqkv, const float* __restrict__ ct, const float* __restrict__ st,
    __hip_bfloat16* __restrict__ qb, __hip_bfloat16* __restrict__ kb,
    __hip_bfloat16* __restrict__ vb) {
  __shared__ char lds[32768];
  const f32x4v fz = {0.f, 0.f, 0.f, 0.f};
  f32x4v acc[4][4];
#pragma unroll
  for (int mf = 0; mf < 4; ++mf)
#pragma unroll
    for (int nf = 0; nf < 4; ++nf) acc[mf][nf] = fz;
  int bx, by;
  xcd_swizzle(bx, by);
  const int brow = by * 128, bcol = bx * 128;
  gemm_tile(A, BT, DIMM, brow, bcol, lds, lds + 16384, acc);

  const int tid = threadIdx.x, lane = tid & 63, wid = tid >> 6;
  const int g = lane >> 4, ln15 = lane & 15;
  const int wr = wid >> 1, wc = wid & 1;
  const int cb = bcol + wc * 64;
  const int which = cb >> 11;
  const int head = (cb & 2047) >> 6;
  float bias[4];
#pragma unroll
  for (int nf = 0; nf < 4; ++nf) bias[nf] = bqkv[cb + nf * 16 + ln15];

  __syncthreads();  // LDS staging done; safe to reuse for transpose

  if (which == 2) {
    // V: transpose wave's 64pos x 64d subtile through LDS, store VT[d][pos] coalesced
    char* tp = lds + wid * 8192;
#pragma unroll
    for (int mf = 0; mf < 4; ++mf)
#pragma unroll
      for (int r = 0; r < 4; ++r) {
        const int posl = mf * 16 + g * 4 + r;
#pragma unroll
        for (int nf = 0; nf < 4; ++nf) {
          const int d = nf * 16 + ln15;
          *(unsigned short*)(tp + d * 128 + ((posl * 2) ^ ((d & 7) << 4))) =
              f2bfu(acc[mf][nf][r] + bias[nf]);
        }
      }
    asm volatile("s_waitcnt lgkmcnt(0)" ::: "memory");
    __builtin_amdgcn_sched_barrier(0);
    const int nidx = brow >> 11;
    const int posb = (brow & 2047) + wr * 64;
    const size_t vhead = ((size_t)nidx * NHEADS + head) * (HDIM * SEQ);
#pragma unroll
    for (int i = 0; i < 8; ++i) {
      const int dl = i * 8 + (lane >> 3);
      const int cs = (lane & 7) ^ (dl & 7);
      const uint4 val = *(const uint4*)(tp + dl * 128 + cs * 16);
      *(uint4*)((char*)vb + (vhead + (size_t)dl * SEQ + posb + (lane & 7) * 8) * 2) = val;
    }
  } else {
    __hip_bfloat16* dst = (which == 0) ? qb : kb;
#pragma unroll
    for (int mf = 0; mf < 4; ++mf)
#pragma unroll
      for (int r = 0; r < 4; ++r) {
        const int row = brow + wr * 64 + mf * 16 + g * 4 + r;
        const int nidx = row >> 11, pos = row & 2047;
        float v0 = acc[mf][0][r] + bias[0];
        float v1 = acc[mf][1][r] + bias[1];
        float v2 = acc[mf][2][r] + bias[2];
        float v3 = acc[mf][3][r] + bias[3];
        const float c0 = ct[pos * 16 + ln15], s0 = st[pos * 16 + ln15];
        const float x1 = v0, x2 = v1;
        v0 = x1 * c0 - x2 * s0;
        v1 = x2 * c0 + x1 * s0;
        __hip_bfloat16* p = dst + (((size_t)(nidx * NHEADS + head)) * SEQ + pos) * HDIM;
        p[ln15] = __float2bfloat16(v0);
        p[16 + ln15] = __float2bfloat16(v1);
        p[32 + ln15] = __float2bfloat16(v2);
        p[48 + ln15] = __float2bfloat16(v3);
      }
  }
}

// ---------------- out-proj GEMM + bias + residual -> f32 out ----------------
__global__ __launch_bounds__(256) void gemm_out_kernel(
    const __hip_bfloat16* __restrict__ A, const __hip_bfloat16* __restrict__ BT,
    const float* __restrict__ bout, const float* __restrict__ skip,
    float* __restrict__ out) {
  __shared__ char lds[32768];
  const f32x4v fz = {0.f, 0.f, 0.f, 0.f};
  f32x4v acc[4][4];
#pragma unroll
  for (int mf = 0; mf < 4; ++mf)
#pragma unroll
    for (int nf = 0; nf < 4; ++nf) acc[mf][nf] = fz;
  int bx, by;
  xcd_swizzle(bx, by);
  const int brow = by * 128, bcol = bx * 128;
  gemm_tile(A, BT, DIMM, brow, bcol, lds, lds + 16384, acc);

  const int tid = threadIdx.x, lane = tid & 63, wid = tid >> 6;
  const int g = lane >> 4, ln15 = lane & 15;
  const int wr = wid >> 1, wc = wid & 1;
#pragma unroll
  for (int mf = 0; mf < 4; ++mf)
#pragma unroll
    for (int r = 0; r < 4; ++r) {
      const int row = brow + wr * 64 + mf * 16 + g * 4 + r;
      const float* xr = skip + (size_t)row * DIMM;
      float* orow = out + (size_t)row * DIMM;
#pragma unroll
      for (int nf = 0; nf < 4; ++nf) {
        const int c = bcol + wc * 64 + nf * 16 + ln15;
        orow[c] = acc[mf][nf][r] + bout[c] + xr[c];
      }
    }
}

// ---------------- causal flash attention, swapped-QK^T 32x32 structure ----------------
// Block: 4 waves x 32 q-rows = 128 q-rows. KV tiles of 64, double-buffered.
// S^T = mfma32(K, Q): lane holds q=lane&31, 16 kv rows per 32-kv tile (other 16 in lane^32).
// Softmax fully in-register; P->A-frags via pack2bf + cross-32 swap; PV uses VT[d][kv] tiles.
__global__ __launch_bounds__(256) void attn_kernel(
    const __hip_bfloat16* __restrict__ qb, const __hip_bfloat16* __restrict__ kb,
    const __hip_bfloat16* __restrict__ vtb, __hip_bfloat16* __restrict__ ob) {
  __shared__ char sm[33280];  // K dbuf 2x8K | VT dbuf 2x8K | lred 512B
  float* lred = (float*)(sm + 32768);
  const int tid = threadIdx.x, lane = tid & 63, wid = tid >> 6;
  const int ln31 = lane & 31, hi = lane >> 5;
  const int head = blockIdx.x;
  const int qbi = (int)gridDim.y - 1 - (int)blockIdx.y;  // heavy blocks dispatch first
  const size_t hb = (size_t)head * (SEQ * HDIM);
  const int q0 = qbi * 128;
  const int qw = q0 + wid * 32;
  const int qg = qw + ln31;
  const int nt = qbi * 2 + 2;
  const char* Kg = (const char*)(kb + hb);
  const char* Vg = (const char*)(vtb + hb);

  // Q fragments (B operand of QK): lane holds row q=ln31, d = j*16 + hi*8 .. +8
  bfv8 qf[4];
  {
    const char* Qp = (const char*)(qb + hb) + (size_t)(qw + ln31) * 128 + hi * 16;
#pragma unroll
    for (int j = 0; j < 4; ++j) qf[j] = *(const bfv8*)(Qp + j * 32);
  }

  f32x16 o0, o1;
#pragma unroll
  for (int i = 0; i < 16; ++i) { o0[i] = 0.f; o1[i] = 0.f; }
  float m_run = -1e30f, l_run = 0.f;
  const float scale = 0.125f;
  const int swz = (ln31 & 7) << 4;

  // prologue: stage tile 0 into buffer 0
#pragma unroll
  for (int i = 0; i < 2; ++i) {
    const int f = (tid + i * 256) * 16;
    const int row = f >> 7;
    const int src = (f & 127) ^ ((row & 7) << 4);
    gload16(Kg + (size_t)row * 128 + src, sm + f);
    gload16(Vg + (size_t)row * 4096 + src, sm + 16384 + f);
  }
  asm volatile("s_waitcnt vmcnt(0)" ::: "memory");
  __syncthreads();

  for (int t = 0; t < nt; ++t) {
    const int kvb = t * 64;
    if (t + 1 < nt) {  // issue next-tile stage early (overlaps with compute)
      const int nb = (t + 1) & 1;
      const int kvb2 = kvb + 64;
#pragma unroll
      for (int i = 0; i < 2; ++i) {
        const int f = (tid + i * 256) * 16;
        const int row = f >> 7;
        const int src = (f & 127) ^ ((row & 7) << 4);
        gload16(Kg + (size_t)(kvb2 + row) * 128 + src, sm + nb * 8192 + f);
        gload16(Vg + (size_t)row * 4096 + (size_t)kvb2 * 2 + src, sm + 16384 + nb * 8192 + f);
      }
    }
    if (kvb <= qw + 31) {  // wave-uniform activity test
      const char* ldsK = sm + (t & 1) * 8192;
      const char* ldsV = sm + 16384 + (t & 1) * 8192;
      f32x16 s0, s1;
#pragma unroll
      for (int i = 0; i < 16; ++i) { s0[i] = 0.f; s1[i] = 0.f; }
      __builtin_amdgcn_s_setprio(1);
#pragma unroll
      for (int j = 0; j < 4; ++j) {
        const int byt = j * 32 + hi * 16;
        const bfv8 k0 = *(const bfv8*)(ldsK + ln31 * 128 + (byt ^ swz));
        const bfv8 k1 = *(const bfv8*)(ldsK + (32 + ln31) * 128 + (byt ^ swz));
        s0 = mfma32(k0, qf[j], s0);
        s1 = mfma32(k1, qf[j], s1);
      }
      __builtin_amdgcn_s_setprio(0);
      float p[32];
#pragma unroll
      for (int r = 0; r < 16; ++r) { p[r] = s0[r] * scale; p[16 + r] = s1[r] * scale; }
      if (kvb + 63 > qw) {  // diagonal tile for this wave: causal mask
        // (trigger must compare against the wave's MIN q-row qw: odd waves hit a
        //  diagonal tile whose end is <= qw+31 but > qw -- R2 bug)
#pragma unroll
        for (int r = 0; r < 16; ++r) {
          const int kvo = (r & 3) + 8 * (r >> 2) + 4 * hi;
          if (kvb + kvo > qg) p[r] = -1e30f;
          if (kvb + 32 + kvo > qg) p[16 + r] = -1e30f;
        }
      }
      float mx = p[0];
#pragma unroll
      for (int r = 1; r < 32; ++r) mx = fmaxf(mx, p[r]);
      mx = fmaxf(mx, __shfl_xor(mx, 32));
      if (!__all(mx <= m_run + 8.0f)) {  // defer-max (T13, THR=8)
        const float mn = fmaxf(m_run, mx);
        const float al = __expf(m_run - mn);
        m_run = mn;
        l_run *= al;
        lred[wid * 32 + ln31] = al;
        asm volatile("s_waitcnt lgkmcnt(0)" ::: "memory");
        __builtin_amdgcn_sched_barrier(0);
#pragma unroll
        for (int r = 0; r < 16; ++r) {
          const float a = lred[wid * 32 + (r & 3) + 8 * (r >> 2) + 4 * hi];
          o0[r] *= a;
          o1[r] *= a;
        }
      }
      float ps = 0.f;
#pragma unroll
      for (int r = 0; r < 32; ++r) { p[r] = __expf(p[r] - m_run); ps += p[r]; }
      ps += __shfl_xor(ps, 32);
      l_run += ps;
      // P -> bf16 A-fragments (kv-16 slices), in-register redistribution
      unsigned c[16];
#pragma unroll
      for (int i = 0; i < 16; ++i) c[i] = pack2bf(p[2 * i], p[2 * i + 1]);
      bfv8 paf[4];
#pragma unroll
      for (int fI = 0; fI < 4; ++fI) {
        unsigned a0 = c[fI * 4 + 0], b0 = c[fI * 4 + 2];
        unsigned a1 = c[fI * 4 + 1], b1 = c[fI * 4 + 3];
        swap32(a0, b0, hi);
        swap32(a1, b1, hi);
        union { unsigned u[4]; bfv8 v; } w;
        w.u[0] = a0; w.u[1] = a1; w.u[2] = b0; w.u[3] = b1;
        paf[fI] = w.v;
      }
      __builtin_amdgcn_s_setprio(1);
#pragma unroll
      for (int ss = 0; ss < 4; ++ss) {
        const int byt = ss * 32 + hi * 16;
        const bfv8 v0 = *(const bfv8*)(ldsV + ln31 * 128 + (byt ^ swz));
        const bfv8 v1 = *(const bfv8*)(ldsV + (32 + ln31) * 128 + (byt ^ swz));
        o0 = mfma32(paf[ss], v0, o0);
        o1 = mfma32(paf[ss], v1, o1);
      }
      __builtin_amdgcn_s_setprio(0);
    }
    asm volatile("s_waitcnt vmcnt(0)" ::: "memory");
    __syncthreads();
  }

  lred[wid * 32 + ln31] = l_run;
  asm volatile("s_waitcnt lgkmcnt(0)" ::: "memory");
  __builtin_amdgcn_sched_barrier(0);
  const int nidx = head >> 5, hh = head & 31;
#pragma unroll
  for (int r = 0; r < 16; ++r) {
    const int qrow = qw + (r & 3) + 8 * (r >> 2) + 4 * hi;
    const float inv = 1.0f / lred[wid * 32 + (r & 3) + 8 * (r >> 2) + 4 * hi];
    __hip_bfloat16* dst = ob + ((size_t)nidx * SEQ + qrow) * DIMM + hh * 64;
    dst[ln31] = __float2bfloat16(o0[r] * inv);
    dst[32 + ln31] = __float2bfloat16(o1[r] * inv);
  }
}

extern "C" void kernel_launch(void* const* d_in, const int* in_sizes, int n_in,
                              void* d_out, int out_size, void* d_ws, size_t ws_size,
                              hipStream_t stream) {
  const float* x = (const float*)d_in[0];
  const float* ln_w = (const float*)d_in[1];
  const float* ln_b = (const float*)d_in[2];
  const float* w_qkv = (const float*)d_in[3];
  const float* b_qkv = (const float*)d_in[4];
  const float* w_out = (const float*)d_in[5];
  const float* b_out = (const float*)d_in[6];
  float* out = (float*)d_out;

  char* ws = (char*)d_ws;
  size_t off = 0;
  auto alloc = [&](size_t bytes) -> char* {
    char* p = ws + off;
    off += (bytes + 255) & ~(size_t)255;
    return p;
  };
  __hip_bfloat16* h = (__hip_bfloat16*)alloc((size_t)ROWS * DIMM * 2);
  __hip_bfloat16* wqkvT = (__hip_bfloat16*)alloc((size_t)3 * DIMM * DIMM * 2);
  __hip_bfloat16* woutT = (__hip_bfloat16*)alloc((size_t)DIMM * DIMM * 2);
  __hip_bfloat16* qbuf = (__hip_bfloat16*)alloc((size_t)ROWS * DIMM * 2);
  __hip_bfloat16* kbuf = (__hip_bfloat16*)alloc((size_t)ROWS * DIMM * 2);
  __hip_bfloat16* vtbuf = (__hip_bfloat16*)alloc((size_t)ROWS * DIMM * 2);
  __hip_bfloat16* obuf = (__hip_bfloat16*)alloc((size_t)ROWS * DIMM * 2);
  float* ct = (float*)alloc((size_t)SEQ * NFREQ * 4);
  float* st = (float*)alloc((size_t)SEQ * NFREQ * 4);

  rope_tab_kernel<<<dim3((SEQ * NFREQ + 255) / 256), dim3(256), 0, stream>>>(ct, st);
  transpose_cast_kernel<<<dim3(3 * DIMM / 32, DIMM / 32), dim3(32, 8), 0, stream>>>(
      w_qkv, wqkvT, DIMM, 3 * DIMM);
  transpose_cast_kernel<<<dim3(DIMM / 32, DIMM / 32), dim3(32, 8), 0, stream>>>(
      w_out, woutT, DIMM, DIMM);
  ln_kernel<<<dim3(ROWS), dim3(256), 0, stream>>>(x, ln_w, ln_b, h);
  gemm_qkv_kernel<<<dim3(3 * DIMM / 128, ROWS / 128), dim3(256), 0, stream>>>(
      h, wqkvT, b_qkv, ct, st, qbuf, kbuf, vtbuf);
  attn_kernel<<<dim3(NBATCH * NHEADS, SEQ / 128), dim3(256), 0, stream>>>(
      qbuf, kbuf, vtbuf, obuf);
  gemm_out_kernel<<<dim3(DIMM / 128, ROWS / 128), dim3(256), 0, stream>>>(
      obuf, woutT, b_out, x, out);
}